// Round 4
// baseline (1606.954 us; speedup 1.0000x reference)
//
#include <hip/hip_runtime.h>
#include <stdint.h>

#define EPS 1e-5f
#define SLOPE 0.01f

typedef short bf16x8 __attribute__((ext_vector_type(8)));
typedef float f32x4 __attribute__((ext_vector_type(4)));

// round-to-nearest-even fp32 -> bf16
__device__ __forceinline__ uint16_t f2bf(float x) {
  union { float f; uint32_t u; } v; v.f = x;
  return (uint16_t)((v.u + 0x7fffu + ((v.u >> 16) & 1u)) >> 16);
}

// async global->LDS, 16B per lane; LDS dest = wave-uniform base + lane*16
__device__ __forceinline__ void g2lds16(const void* g, void* l) {
  __builtin_amdgcn_global_load_lds(
      (const __attribute__((address_space(1))) void*)g,
      (__attribute__((address_space(3))) void*)l, 16, 0, 0);
}

// ---------------------------------------------------------------------------
// prep: bn scale/bias folding.  s = g/sqrt(v+eps), beta = b - m*s.
// For the point-MLP bn, bo1 is folded in: beta_o = bo + (bo1 - mo)*s.
// ---------------------------------------------------------------------------
__global__ void prep_bn(const float* g1, const float* b1, const float* m1, const float* v1,
                        const float* g2, const float* b2, const float* m2, const float* v2,
                        const float* g3, const float* b3, const float* m3, const float* v3,
                        const float* go, const float* bo, const float* mo, const float* vo,
                        const float* bo1,
                        float* s1, float* be1, float* s2, float* be2,
                        float* s3, float* be3, float* so, float* beo) {
  int t = threadIdx.x;
  if (t < 256) { float s = g1[t] / sqrtf(v1[t] + EPS); s1[t] = s; be1[t] = b1[t] - m1[t] * s; }
  if (t < 64)  { float s = g2[t] / sqrtf(v2[t] + EPS); s2[t] = s; be2[t] = b2[t] - m2[t] * s; }
  if (t < 32)  { float s = g3[t] / sqrtf(v3[t] + EPS); s3[t] = s; be3[t] = b3[t] - m3[t] * s; }
  if (t < 32)  { float s = go[t] / sqrtf(vo[t] + EPS); so[t] = s; beo[t] = bo[t] + (bo1[t] - mo[t]) * s; }
}

// ---------------------------------------------------------------------------
// weight transform: W[co][ci][27] fp32 -> Wt[t][co][ci] bf16
// ---------------------------------------------------------------------------
__global__ void wtrans(const float* __restrict__ W, uint16_t* __restrict__ Wt,
                       int CO, int CI) {
  int idx = blockIdx.x * 256 + threadIdx.x;
  int total = CO * CI * 27;
  if (idx >= total) return;
  int t = idx / (CO * CI);
  int rem = idx % (CO * CI);
  int co = rem / CI, ci = rem % CI;
  Wt[idx] = f2bf(W[((size_t)co * CI + ci) * 27 + t]);
}

// ---------------------------------------------------------------------------
// halo zero: padded buffer [NB][66][66][18][C] (C bf16 ch) — zero cells where
// d==0|65 || h==0|65 || w==0|17.  One block per (nb, dpad) slab; 8 threads
// per cell, each writes C/8 elems (C=256 -> 64B, C=64 -> 16B).
// ---------------------------------------------------------------------------
__global__ __launch_bounds__(256) void halo_zero(uint16_t* __restrict__ base, int C) {
  int dpad = blockIdx.x % 66;
  int bd = blockIdx.x / 66;
  uint16_t* slab = base + ((size_t)bd * 78408 + (size_t)dpad * 1188) * C;
  int t = threadIdx.x;
  int tc = t & 7;
  bool dHalo = (dpad == 0) | (dpad == 65);
  int n4 = C >> 6;  // uint4s per chunk
  for (int cell = t >> 3; cell < 1188; cell += 32) {
    int hp = cell / 18, wp = cell % 18;
    if (!(dHalo || hp == 0 || hp == 65 || wp == 0 || wp == 17)) continue;
    uint4* q = (uint4*)(slab + (size_t)cell * C + tc * (C >> 3));
    for (int i = 0; i < n4; ++i) q[i] = make_uint4(0, 0, 0, 0);
  }
}

// ---------------------------------------------------------------------------
// fea NCDHW fp32 -> pad0 NDHWC bf16, padded dims [66][66][18][256].
// Register transpose: fully-coalesced fp32 reads (lane-contiguous spatial);
// each thread emits a contiguous 256B bf16 run (full cache lines on write).
// ---------------------------------------------------------------------------
__global__ __launch_bounds__(256) void transpose_fea(const float* __restrict__ fea,
                                                     uint16_t* __restrict__ pad0) {
  int tid = threadIdx.x;
  int idx = blockIdx.x;
  int half = idx & 1;
  int q = (idx >> 1) & 3;
  int d = (idx >> 3) & 63;
  int b = idx >> 9;
  int s = q * 256 + tid;               // h*16+w within the d-slice
  int h = s >> 4, w = s & 15;
  const float* src = fea + (size_t)(b * 256 + half * 128) * 65536 + (size_t)d * 1024 + s;
  uint16_t* dst = pad0 + ((size_t)b * 78408 +
                          (size_t)((d + 1) * 1188 + (h + 1) * 18 + (w + 1))) * 256 + half * 128;
#pragma unroll 4
  for (int c8 = 0; c8 < 16; ++c8) {
    uint16_t v[8];
#pragma unroll
    for (int j = 0; j < 8; ++j)
      v[j] = f2bf(src[(size_t)(c8 * 8 + j) * 65536]);
    *(uint4*)&dst[c8 * 8] = *(uint4*)v;
  }
}

// ---------------------------------------------------------------------------
// Implicit-GEMM 3x3x3 conv, NDHWC padded bf16, mfma_f32_16x16x32_bf16,
// fused BN+LeakyReLU.
//   A (activations): staged in LDS once per (kd,kh,kc) as w-extended rows
//     [w'=0..17][mh][64ci], reused for kw=0,1,2 (XOR-swizzled, conflict-free).
//   B (weights): NOT in LDS — fragments loaded straight from global into
//     VGPRs (L2-resident: every block reads the same 3.5MB stream). Address =
//     sgpr-uniform offset + one per-lane voffset; software-pipelined one
//     k-step ahead (bcur/bnxt) so the compiler emits fine-grained vmcnt.
//   Barriers: only around A staging — 1 per (dh,kc) instead of 3.
// ---------------------------------------------------------------------------
template <int CI, int CO, int MH, int WM, int WN, bool LAST>
__global__ __launch_bounds__(256, 2) void conv_mfma(const uint16_t* __restrict__ padIn,
                                                    const uint16_t* __restrict__ Wt,
                                                    const float* __restrict__ bnS,
                                                    const float* __restrict__ bnB,
                                                    uint16_t* __restrict__ padOut,
                                                    float* __restrict__ x3out) {
  constexpr int NTILE = CO;
  constexpr int MTILE = MH * 16;
  constexpr int MPW = MTILE / WM;
  constexpr int NPW = NTILE / WN;
  constexpr int MSUB = MPW / 16;
  constexpr int NSUB = NPW / 16;
  constexpr int KC = CI / 64;
  constexpr int HB = 64 / MH;
  constexpr int HALF = MH / 8;
  constexpr int ROWSTR = 18 * CI;   // padded w-row stride (elements)

  __shared__ __align__(16) uint16_t Alds[20 * MH * 64];  // [w'][mh][ci64]; w' 18,19 dummy

  const int tid = threadIdx.x;
  const int lane = tid & 63;
  const int wv = tid >> 6;
  const int wvm = wv / WN;
  const int wvn = wv % WN;

  const int mt = blockIdx.x;
  const int b = mt / (64 * HB);
  const int r = mt % (64 * HB);
  const int d = r / HB;
  const int h0 = (r % HB) * MH;

  // per-lane B voffset (elements): row-within-16 x CI + k-quad x 8
  const size_t laneOffB = (size_t)(lane & 15) * CI + (size_t)(lane >> 4) * 8;
  const size_t nOffU = (size_t)(wvn * NPW) * CI;  // wave-uniform

  f32x4 acc[MSUB][NSUB] = {};

  const size_t bOffIn = (size_t)b * 78408 * CI;

  for (int dh = 0; dh < 9; ++dh) {
    const int kd = dh / 3, kh = dh % 3;
    const size_t Abase = bOffIn + (size_t)((d + kd) * 1188 + (h0 + kh) * 18) * CI;
    for (int kc = 0; kc < KC; ++kc) {
      __syncthreads();  // previous epoch's A reads done
      {
        // stage A_ext: wave wv covers w'-slots wv*5..wv*5+4 (20 incl. dummies),
        // lanes: mh=lane>>3, unit=lane&7; unit stored at (u ^ (w'&7))
        const uint16_t* agBase = padIn + Abase + kc * 64 + (size_t)(lane >> 3) * ROWSTR;
#pragma unroll
        for (int p = 0; p < 5; ++p) {
          int wp = wv * 5 + p;
          int gu = (lane & 7) ^ (wp & 7);
#pragma unroll
          for (int hf = 0; hf < HALF; ++hf)
            g2lds16(agBase + (size_t)(hf * 8) * ROWSTR + wp * CI + gu * 8,
                    (char*)Alds + wp * (MH * 128) + hf * 1024);
        }
      }
      __syncthreads();  // staging DMA drained

      // uniform B offsets for the 6 k-steps (kw x ks) of this (dh,kc)
      int offs[6];
#pragma unroll
      for (int s = 0; s < 6; ++s)
        offs[s] = ((dh * 3 + (s >> 1)) * CO) * CI + kc * 64 + (s & 1) * 32;

      bf16x8 bcur[NSUB], bnxt[NSUB];
#pragma unroll
      for (int ni = 0; ni < NSUB; ++ni)
        bcur[ni] = *(const bf16x8*)(Wt + (size_t)offs[0] + nOffU + (size_t)(ni * 16) * CI + laneOffB);

#pragma unroll
      for (int s = 0; s < 6; ++s) {
        const int kw = s >> 1, ks = s & 1;
        if (s < 5) {
#pragma unroll
          for (int ni = 0; ni < NSUB; ++ni)
            bnxt[ni] = *(const bf16x8*)(Wt + (size_t)offs[s + 1] + nOffU + (size_t)(ni * 16) * CI + laneOffB);
        }
        bf16x8 af[MSUB];
#pragma unroll
        for (int mi = 0; mi < MSUB; ++mi) {
          int wq = (lane & 15) + kw;
          int u = (ks * 4 + (lane >> 4)) ^ (wq & 7);
          int mhIdx = wvm * MSUB + mi;
          af[mi] = *(const bf16x8*)&Alds[wq * (MH * 64) + mhIdx * 64 + u * 8];
        }
#pragma unroll
        for (int mi = 0; mi < MSUB; ++mi)
#pragma unroll
          for (int ni = 0; ni < NSUB; ++ni)
            acc[mi][ni] = __builtin_amdgcn_mfma_f32_16x16x32_bf16(af[mi], bcur[ni], acc[mi][ni], 0, 0, 0);
        if (s < 5) {
#pragma unroll
          for (int ni = 0; ni < NSUB; ++ni) bcur[ni] = bnxt[ni];
        }
      }
    }
  }

  // epilogue: y = x*s + beta, LeakyReLU; C/D layout col=lane&15, row=quad*4+r
  const int col = lane & 15;
  const int quad = lane >> 4;
#pragma unroll
  for (int ni = 0; ni < NSUB; ++ni) {
    const int co = wvn * NPW + ni * 16 + col;
    const float sv = bnS[co];
    const float bv = bnB[co];
#pragma unroll
    for (int mi = 0; mi < MSUB; ++mi) {
#pragma unroll
      for (int rr = 0; rr < 4; ++rr) {
        int m = wvm * MPW + mi * 16 + quad * 4 + rr;
        float v = acc[mi][ni][rr] * sv + bv;
        v = v > 0.f ? v : SLOPE * v;
        int mh = m >> 4, w = m & 15;
        if (!LAST) {
          size_t o = ((size_t)b * 78408 +
                      (size_t)((d + 1) * 1188 + (h0 + mh + 1) * 18 + (w + 1))) * CO + co;
          padOut[o] = f2bf(v);
        } else {
          size_t o = ((size_t)b * 65536 + (size_t)((d * 64 + h0 + mh) * 16 + w)) * 32 + co;
          x3out[o] = v;
        }
      }
    }
  }
}

// ---------------------------------------------------------------------------
// gather + point MLP, all fp32. One thread per point.
// ---------------------------------------------------------------------------
__global__ __launch_bounds__(256) void gather_mlp(const float* __restrict__ x3,
                                                  const int* __restrict__ gidx,
                                                  const float* __restrict__ xyz,
                                                  const float* __restrict__ Wo1,
                                                  const float* __restrict__ so,
                                                  const float* __restrict__ beo,
                                                  const float* __restrict__ Wo2,
                                                  const float* __restrict__ bo2,
                                                  float* __restrict__ out) {
  __shared__ __align__(16) float w1[35 * 32];
  __shared__ float w2[32 * 3];
  __shared__ float sS[32], sB[32], b2s[3];
  int tid = threadIdx.x;
  for (int i = tid; i < 1120; i += 256) w1[i] = Wo1[i];
  if (tid < 96) w2[tid] = Wo2[tid];
  if (tid < 32) { sS[tid] = so[tid]; sB[tid] = beo[tid]; }
  if (tid < 3) b2s[tid] = bo2[tid];
  __syncthreads();

  int idx = blockIdx.x * 256 + tid;
  if (idx >= 200000) return;
  int b = idx >= 100000 ? 1 : 0;
  int gb = idx * 3;
  int i0 = gidx[gb], i1 = gidx[gb + 1], i2 = gidx[gb + 2];
  const float* pt = x3 + ((size_t)b * 65536 + (size_t)((i0 * 64 + i1) * 16 + i2)) * 32;

  float h[35];
#pragma unroll
  for (int q = 0; q < 8; ++q) {
    float4 v = *(const float4*)(pt + q * 4);
    h[q * 4] = v.x; h[q * 4 + 1] = v.y; h[q * 4 + 2] = v.z; h[q * 4 + 3] = v.w;
  }
  h[32] = xyz[gb]; h[33] = xyz[gb + 1]; h[34] = xyz[gb + 2];

  float a[32];
#pragma unroll
  for (int j = 0; j < 32; ++j) a[j] = 0.f;
#pragma unroll
  for (int k = 0; k < 35; ++k) {
    float hk = h[k];
    const float4* wr = (const float4*)(w1 + k * 32);
#pragma unroll
    for (int q = 0; q < 8; ++q) {
      float4 wv = wr[q];
      a[q * 4 + 0] += hk * wv.x;
      a[q * 4 + 1] += hk * wv.y;
      a[q * 4 + 2] += hk * wv.z;
      a[q * 4 + 3] += hk * wv.w;
    }
  }
  float o0 = b2s[0], o1 = b2s[1], o2 = b2s[2];
#pragma unroll
  for (int j = 0; j < 32; ++j) {
    float y = a[j] * sS[j] + sB[j];
    y = y > 0.f ? y : 0.f;
    o0 += y * w2[j * 3 + 0];
    o1 += y * w2[j * 3 + 1];
    o2 += y * w2[j * 3 + 2];
  }
  out[gb] = o0; out[gb + 1] = o1; out[gb + 2] = o2;
}

// ---------------------------------------------------------------------------
// workspace layout (bytes):
//   pad0: 0            .. 80,289,792   (2*78408*256*2)
//         [after conv1: pad2 @0 (20,072,448), x3 @20,072,448 (16,777,216)]
//   pad1: 80,289,792   .. 160,579,584
//   Wt1 : 160,579,584  (3,538,944)
//   Wt2 : 164,118,528  (884,736)
//   Wt3 : 165,003,264  (110,592)
//   bn  : 165,113,856  (8 slots x 1024B)
// total ~165.2 MB.  (A-staging dummy slots may read <=1KB past a pad
// buffer's end — always into the next ws region, never past ws.)
// ---------------------------------------------------------------------------
extern "C" void kernel_launch(void* const* d_in, const int* in_sizes, int n_in,
                              void* d_out, int out_size, void* d_ws, size_t ws_size,
                              hipStream_t stream) {
  (void)in_sizes; (void)n_in; (void)out_size;
  if (ws_size < 165130000) return;  // workspace too small — bail loudly (absmax will fail)

  const float* fea = (const float*)d_in[0];
  const int*   gidx = (const int*)d_in[1];
  const float* xyz = (const float*)d_in[2];
  const float* W1 = (const float*)d_in[3];
  const float* g1 = (const float*)d_in[4];
  const float* b1 = (const float*)d_in[5];
  const float* m1 = (const float*)d_in[6];
  const float* v1 = (const float*)d_in[7];
  const float* W2 = (const float*)d_in[8];
  const float* g2 = (const float*)d_in[9];
  const float* b2 = (const float*)d_in[10];
  const float* m2 = (const float*)d_in[11];
  const float* v2 = (const float*)d_in[12];
  const float* W3 = (const float*)d_in[13];
  const float* g3 = (const float*)d_in[14];
  const float* b3 = (const float*)d_in[15];
  const float* m3 = (const float*)d_in[16];
  const float* v3 = (const float*)d_in[17];
  const float* Wo1 = (const float*)d_in[18];
  const float* bo1 = (const float*)d_in[19];
  const float* go = (const float*)d_in[20];
  const float* bo = (const float*)d_in[21];
  const float* mo = (const float*)d_in[22];
  const float* vo = (const float*)d_in[23];
  const float* Wo2 = (const float*)d_in[24];
  const float* bo2 = (const float*)d_in[25];

  char* ws = (char*)d_ws;
  uint16_t* pad0 = (uint16_t*)(ws);
  uint16_t* pad1 = (uint16_t*)(ws + 80289792);
  uint16_t* Wt1 = (uint16_t*)(ws + 160579584);
  uint16_t* Wt2 = (uint16_t*)(ws + 164118528);
  uint16_t* Wt3 = (uint16_t*)(ws + 165003264);
  float* s1  = (float*)(ws + 165113856 + 0 * 1024);
  float* be1 = (float*)(ws + 165113856 + 1 * 1024);
  float* s2  = (float*)(ws + 165113856 + 2 * 1024);
  float* be2 = (float*)(ws + 165113856 + 3 * 1024);
  float* s3  = (float*)(ws + 165113856 + 4 * 1024);
  float* be3 = (float*)(ws + 165113856 + 5 * 1024);
  float* so  = (float*)(ws + 165113856 + 6 * 1024);
  float* beo = (float*)(ws + 165113856 + 7 * 1024);
  // aliases into pad0's region (pad0 is dead after conv1)
  uint16_t* pad2 = (uint16_t*)(ws);
  float* x3 = (float*)(ws + 20072448);

  prep_bn<<<1, 256, 0, stream>>>(g1, b1, m1, v1, g2, b2, m2, v2, g3, b3, m3, v3,
                                 go, bo, mo, vo, bo1, s1, be1, s2, be2, s3, be3, so, beo);
  wtrans<<<6912, 256, 0, stream>>>(W1, Wt1, 256, 256);
  wtrans<<<1728, 256, 0, stream>>>(W2, Wt2, 64, 256);
  wtrans<<<216, 256, 0, stream>>>(W3, Wt3, 32, 64);
  // pad0+pad1 halos (contiguous, 4 b-slabs of [66][66][18][256])
  halo_zero<<<264, 256, 0, stream>>>((uint16_t*)ws, 256);
  transpose_fea<<<1024, 256, 0, stream>>>(fea, pad0);

  // conv1: CI=256, CO=256, MH=8 (MTILE=128), waves 2x2, per-wave 64x128
  conv_mfma<256, 256, 8, 2, 2, false>
      <<<1024, 256, 0, stream>>>(pad0, Wt1, s1, be1, pad1, nullptr);

  // pad2 halo (aliases pad0 region; pad0 dead after conv1 — stream-ordered)
  halo_zero<<<132, 256, 0, stream>>>((uint16_t*)ws, 64);

  // conv2: CI=256, CO=64, MH=16 (MTILE=256), waves 4x1, per-wave 64x64
  conv_mfma<256, 64, 16, 4, 1, false>
      <<<512, 256, 0, stream>>>(pad1, Wt2, s2, be2, pad2, nullptr);

  // conv3: CI=64, CO=32, MH=16 (MTILE=256), waves 4x1, per-wave 64x32
  conv_mfma<64, 32, 16, 4, 1, true>
      <<<512, 256, 0, stream>>>(pad2, Wt3, s3, be3, nullptr, x3);

  gather_mlp<<<782, 256, 0, stream>>>(x3, gidx, xyz, Wo1, so, beo, Wo2, bo2, (float*)d_out);
}

// Round 5
// 1433.540 us; speedup vs baseline: 1.1210x; 1.1210x over previous
//
#include <hip/hip_runtime.h>
#include <stdint.h>

#define EPS 1e-5f
#define SLOPE 0.01f

typedef short bf16x8 __attribute__((ext_vector_type(8)));
typedef float f32x4 __attribute__((ext_vector_type(4)));

// round-to-nearest-even fp32 -> bf16
__device__ __forceinline__ uint16_t f2bf(float x) {
  union { float f; uint32_t u; } v; v.f = x;
  return (uint16_t)((v.u + 0x7fffu + ((v.u >> 16) & 1u)) >> 16);
}

// async global->LDS, 16B per lane; LDS dest = wave-uniform base + lane*16
__device__ __forceinline__ void g2lds16(const void* g, void* l) {
  __builtin_amdgcn_global_load_lds(
      (const __attribute__((address_space(1))) void*)g,
      (__attribute__((address_space(3))) void*)l, 16, 0, 0);
}

// ---------------------------------------------------------------------------
// prep: bn scale/bias folding.
// ---------------------------------------------------------------------------
__global__ void prep_bn(const float* g1, const float* b1, const float* m1, const float* v1,
                        const float* g2, const float* b2, const float* m2, const float* v2,
                        const float* g3, const float* b3, const float* m3, const float* v3,
                        const float* go, const float* bo, const float* mo, const float* vo,
                        const float* bo1,
                        float* s1, float* be1, float* s2, float* be2,
                        float* s3, float* be3, float* so, float* beo) {
  int t = threadIdx.x;
  if (t < 256) { float s = g1[t] / sqrtf(v1[t] + EPS); s1[t] = s; be1[t] = b1[t] - m1[t] * s; }
  if (t < 64)  { float s = g2[t] / sqrtf(v2[t] + EPS); s2[t] = s; be2[t] = b2[t] - m2[t] * s; }
  if (t < 32)  { float s = g3[t] / sqrtf(v3[t] + EPS); s3[t] = s; be3[t] = b3[t] - m3[t] * s; }
  if (t < 32)  { float s = go[t] / sqrtf(vo[t] + EPS); so[t] = s; beo[t] = bo[t] + (bo1[t] - mo[t]) * s; }
}

// ---------------------------------------------------------------------------
// weight transform to CONSUMPTION order:
// Wpk[step][co][32ci] bf16, step = ((dh*KC + kc)*3 + kw)*2 + half,
// ci = kc*64 + half*32 + j, tap = dh*3 + kw.  W is [CO][CI][27] fp32.
// The conv kernel's B staging then walks Wpk strictly sequentially.
// ---------------------------------------------------------------------------
__global__ void wtrans(const float* __restrict__ W, uint16_t* __restrict__ Wt,
                       int CO, int CI, int KC) {
  int idx = blockIdx.x * 256 + threadIdx.x;
  int total = CO * CI * 27;
  if (idx >= total) return;
  int step = idx / (CO * 32);
  int rem = idx % (CO * 32);
  int co = rem / 32, j = rem % 32;
  int half = step & 1, u = step >> 1;
  int kw = u % 3, v = u / 3;
  int kc = v % KC, dh = v / KC;
  int ci = kc * 64 + half * 32 + j;
  int t = dh * 3 + kw;
  Wt[idx] = f2bf(W[((size_t)co * CI + ci) * 27 + t]);
}

// ---------------------------------------------------------------------------
// halo zero: padded buffer [NB][66][66][18][C] — zero d/h/w halo cells.
// ---------------------------------------------------------------------------
__global__ __launch_bounds__(256) void halo_zero(uint16_t* __restrict__ base, int C) {
  int dpad = blockIdx.x % 66;
  int bd = blockIdx.x / 66;
  uint16_t* slab = base + ((size_t)bd * 78408 + (size_t)dpad * 1188) * C;
  int t = threadIdx.x;
  int tc = t & 7;
  bool dHalo = (dpad == 0) | (dpad == 65);
  int n4 = C >> 6;
  for (int cell = t >> 3; cell < 1188; cell += 32) {
    int hp = cell / 18, wp = cell % 18;
    if (!(dHalo || hp == 0 || hp == 65 || wp == 0 || wp == 17)) continue;
    uint4* q = (uint4*)(slab + (size_t)cell * C + tc * (C >> 3));
    for (int i = 0; i < n4; ++i) q[i] = make_uint4(0, 0, 0, 0);
  }
}

// ---------------------------------------------------------------------------
// fea NCDHW fp32 -> pad0 NDHWC bf16, padded dims [66][66][18][256].
// ---------------------------------------------------------------------------
__global__ __launch_bounds__(256) void transpose_fea(const float* __restrict__ fea,
                                                     uint16_t* __restrict__ pad0) {
  int tid = threadIdx.x;
  int idx = blockIdx.x;
  int half = idx & 1;
  int q = (idx >> 1) & 3;
  int d = (idx >> 3) & 63;
  int b = idx >> 9;
  int s = q * 256 + tid;
  int h = s >> 4, w = s & 15;
  const float* src = fea + (size_t)(b * 256 + half * 128) * 65536 + (size_t)d * 1024 + s;
  uint16_t* dst = pad0 + ((size_t)b * 78408 +
                          (size_t)((d + 1) * 1188 + (h + 1) * 18 + (w + 1))) * 256 + half * 128;
#pragma unroll 4
  for (int c8 = 0; c8 < 16; ++c8) {
    uint16_t v[8];
#pragma unroll
    for (int j = 0; j < 8; ++j)
      v[j] = f2bf(src[(size_t)(c8 * 8 + j) * 65536]);
    *(uint4*)&dst[c8 * 8] = *(uint4*)v;
  }
}

// ---------------------------------------------------------------------------
// Implicit-GEMM 3x3x3 conv, pipelined B staging.
//   A: LDS, BK=64, kw-extended rows [w'0..17][mh][ci64], staged once per
//      (dh,kc), reused kw=0,1,2.  XOR swizzle u^(w'&7) (r3-proven).
//   B: K=32 steps; Wpk consumed sequentially; 16KB staged ONE STEP AHEAD
//      into alternating SEPARATE __shared__ arrays Blds0/Blds1 (kw/half
//      unrolled so every LDS ref is compile-time disambiguated -> the
//      barrier at step s+1 drains a DMA issued a full compute-step earlier).
//   B-read swizzle: u = quad ^ ((row>>1)&3) -> 64B rows, 2-way free.
// ---------------------------------------------------------------------------
template <int CI, int CO, int MH, int WM, int WN, bool LAST>
__global__ __launch_bounds__(256, 2) void conv_mfma(const uint16_t* __restrict__ padIn,
                                                    const uint16_t* __restrict__ Wpk,
                                                    const float* __restrict__ bnS,
                                                    const float* __restrict__ bnB,
                                                    uint16_t* __restrict__ padOut,
                                                    float* __restrict__ x3out) {
  constexpr int NTILE = CO;
  constexpr int MTILE = MH * 16;
  constexpr int MPW = MTILE / WM;
  constexpr int NPW = NTILE / WN;
  constexpr int MSUB = MPW / 16;
  constexpr int NSUB = NPW / 16;
  constexpr int KC = CI / 64;
  constexpr int HB = 64 / MH;
  constexpr int AHI = MH / 8;          // A staging instrs per w'-slot
  constexpr int ROWSTR = 18 * CI;
  constexpr int NSTEPS = 9 * KC * 6;
  constexpr int BI = CO / 16;          // B staging 1KB-instrs per step
  constexpr int BIW = (BI + 3) / 4;    // per wave

  __shared__ __align__(16) uint16_t Alds[20 * MH * 64];
  __shared__ __align__(16) uint16_t Blds0[CO * 32];
  __shared__ __align__(16) uint16_t Blds1[CO * 32];

  const int tid = threadIdx.x;
  const int lane = tid & 63;
  const int wv = tid >> 6;
  const int wvm = wv / WN;
  const int wvn = wv % WN;

  const int mt = blockIdx.x;
  const int b = mt / (64 * HB);
  const int r = mt % (64 * HB);
  const int d = r / HB;
  const int h0 = (r % HB) * MH;

  f32x4 acc[MSUB][NSUB] = {};

  const size_t bOffIn = (size_t)b * 78408 * CI;

// stage 16KB (CO x 32ci) of Wpk step `SOFF` into LDS array DST
#define STAGE_B(DST, SOFF)                                                \
  {                                                                       \
    const uint16_t* bg = Wpk + (size_t)(SOFF) * (CO * 32);                \
    _Pragma("unroll")                                                     \
    for (int p = 0; p < BIW; ++p) {                                       \
      int bidx = wv * BIW + p;                                            \
      if (BI >= 4 || bidx < BI) {                                         \
        int row = bidx * 16 + (lane >> 2);                                \
        int gu = (lane & 3) ^ ((row >> 1) & 3);                           \
        g2lds16(bg + (size_t)row * 32 + gu * 8,                           \
                (char*)(DST) + bidx * 1024);                              \
      }                                                                   \
    }                                                                     \
  }

// one K=32 compute step reading A (KW,HF window) and B from BBUF
#define COMPUTE_STEP(KW, HF, BBUF)                                        \
  {                                                                       \
    bf16x8 af[MSUB], bfr[NSUB];                                           \
    _Pragma("unroll")                                                     \
    for (int ni = 0; ni < NSUB; ++ni) {                                   \
      int row = wvn * NPW + ni * 16 + (lane & 15);                        \
      int u = (lane >> 4) ^ ((row >> 1) & 3);                             \
      bfr[ni] = *(const bf16x8*)&(BBUF)[row * 32 + u * 8];                \
    }                                                                     \
    _Pragma("unroll")                                                     \
    for (int mi = 0; mi < MSUB; ++mi) {                                   \
      int wq = (lane & 15) + (KW);                                        \
      int u = ((HF) * 4 + (lane >> 4)) ^ (wq & 7);                        \
      af[mi] = *(const bf16x8*)&Alds[wq * (MH * 64) +                     \
                                     (wvm * MSUB + mi) * 64 + u * 8];     \
    }                                                                     \
    _Pragma("unroll")                                                     \
    for (int mi = 0; mi < MSUB; ++mi)                                     \
      _Pragma("unroll")                                                   \
      for (int ni = 0; ni < NSUB; ++ni)                                   \
        acc[mi][ni] = __builtin_amdgcn_mfma_f32_16x16x32_bf16(            \
            af[mi], bfr[ni], acc[mi][ni], 0, 0, 0);                       \
  }

  // preload B[0]
  STAGE_B(Blds0, 0);

  for (int dh = 0; dh < 9; ++dh) {
    const int kd = dh / 3, kh = dh % 3;
    const size_t Abase = bOffIn + (size_t)((d + kd) * 1188 + (h0 + kh) * 18) * CI;
    for (int kc = 0; kc < KC; ++kc) {
      const int sBase = (dh * KC + kc) * 6;   // linear step of (kw=0,half=0)

      // ---- kw=0, half=0 : A restage + drain, then pipeline B[s+1]
      __syncthreads();
      {
        const uint16_t* agBase = padIn + Abase + kc * 64 + (size_t)(lane >> 3) * ROWSTR;
#pragma unroll
        for (int p = 0; p < 5; ++p) {
          int wp = wv * 5 + p;
          int gu = (lane & 7) ^ (wp & 7);
#pragma unroll
          for (int hf = 0; hf < AHI; ++hf)
            g2lds16(agBase + (size_t)(hf * 8) * ROWSTR + wp * CI + gu * 8,
                    (char*)Alds + wp * (MH * 128) + hf * 1024);
        }
      }
      __syncthreads();                        // drain A DMA (B[s] long since drained)
      STAGE_B(Blds1, sBase + 1);
      COMPUTE_STEP(0, 0, Blds0);

      // ---- kw=0, half=1
      __syncthreads();
      STAGE_B(Blds0, sBase + 2);
      COMPUTE_STEP(0, 1, Blds1);

      // ---- kw=1, half=0
      __syncthreads();
      STAGE_B(Blds1, sBase + 3);
      COMPUTE_STEP(1, 0, Blds0);

      // ---- kw=1, half=1
      __syncthreads();
      STAGE_B(Blds0, sBase + 4);
      COMPUTE_STEP(1, 1, Blds1);

      // ---- kw=2, half=0
      __syncthreads();
      STAGE_B(Blds1, sBase + 5);
      COMPUTE_STEP(2, 0, Blds0);

      // ---- kw=2, half=1 (guard final prefetch)
      __syncthreads();
      if (sBase + 6 < NSTEPS) STAGE_B(Blds0, sBase + 6);
      COMPUTE_STEP(2, 1, Blds1);
    }
  }
#undef STAGE_B
#undef COMPUTE_STEP

  // epilogue: y = x*s + beta, LeakyReLU; C/D layout col=lane&15, row=quad*4+r
  const int col = lane & 15;
  const int quad = lane >> 4;
#pragma unroll
  for (int ni = 0; ni < NSUB; ++ni) {
    const int co = wvn * NPW + ni * 16 + col;
    const float sv = bnS[co];
    const float bv = bnB[co];
#pragma unroll
    for (int mi = 0; mi < MSUB; ++mi) {
#pragma unroll
      for (int rr = 0; rr < 4; ++rr) {
        int m = wvm * MPW + mi * 16 + quad * 4 + rr;
        float v = acc[mi][ni][rr] * sv + bv;
        v = v > 0.f ? v : SLOPE * v;
        int mh = m >> 4, w = m & 15;
        if (!LAST) {
          size_t o = ((size_t)b * 78408 +
                      (size_t)((d + 1) * 1188 + (h0 + mh + 1) * 18 + (w + 1))) * CO + co;
          padOut[o] = f2bf(v);
        } else {
          size_t o = ((size_t)b * 65536 + (size_t)((d * 64 + h0 + mh) * 16 + w)) * 32 + co;
          x3out[o] = v;
        }
      }
    }
  }
}

// ---------------------------------------------------------------------------
// gather + point MLP, all fp32. One thread per point.
// ---------------------------------------------------------------------------
__global__ __launch_bounds__(256) void gather_mlp(const float* __restrict__ x3,
                                                  const int* __restrict__ gidx,
                                                  const float* __restrict__ xyz,
                                                  const float* __restrict__ Wo1,
                                                  const float* __restrict__ so,
                                                  const float* __restrict__ beo,
                                                  const float* __restrict__ Wo2,
                                                  const float* __restrict__ bo2,
                                                  float* __restrict__ out) {
  __shared__ __align__(16) float w1[35 * 32];
  __shared__ float w2[32 * 3];
  __shared__ float sS[32], sB[32], b2s[3];
  int tid = threadIdx.x;
  for (int i = tid; i < 1120; i += 256) w1[i] = Wo1[i];
  if (tid < 96) w2[tid] = Wo2[tid];
  if (tid < 32) { sS[tid] = so[tid]; sB[tid] = beo[tid]; }
  if (tid < 3) b2s[tid] = bo2[tid];
  __syncthreads();

  int idx = blockIdx.x * 256 + tid;
  if (idx >= 200000) return;
  int b = idx >= 100000 ? 1 : 0;
  int gb = idx * 3;
  int i0 = gidx[gb], i1 = gidx[gb + 1], i2 = gidx[gb + 2];
  const float* pt = x3 + ((size_t)b * 65536 + (size_t)((i0 * 64 + i1) * 16 + i2)) * 32;

  float h[35];
#pragma unroll
  for (int q = 0; q < 8; ++q) {
    float4 v = *(const float4*)(pt + q * 4);
    h[q * 4] = v.x; h[q * 4 + 1] = v.y; h[q * 4 + 2] = v.z; h[q * 4 + 3] = v.w;
  }
  h[32] = xyz[gb]; h[33] = xyz[gb + 1]; h[34] = xyz[gb + 2];

  float a[32];
#pragma unroll
  for (int j = 0; j < 32; ++j) a[j] = 0.f;
#pragma unroll
  for (int k = 0; k < 35; ++k) {
    float hk = h[k];
    const float4* wr = (const float4*)(w1 + k * 32);
#pragma unroll
    for (int q = 0; q < 8; ++q) {
      float4 wv = wr[q];
      a[q * 4 + 0] += hk * wv.x;
      a[q * 4 + 1] += hk * wv.y;
      a[q * 4 + 2] += hk * wv.z;
      a[q * 4 + 3] += hk * wv.w;
    }
  }
  float o0 = b2s[0], o1 = b2s[1], o2 = b2s[2];
#pragma unroll
  for (int j = 0; j < 32; ++j) {
    float y = a[j] * sS[j] + sB[j];
    y = y > 0.f ? y : 0.f;
    o0 += y * w2[j * 3 + 0];
    o1 += y * w2[j * 3 + 1];
    o2 += y * w2[j * 3 + 2];
  }
  out[gb] = o0; out[gb + 1] = o1; out[gb + 2] = o2;
}

// ---------------------------------------------------------------------------
// workspace layout (bytes): unchanged from r3.
// ---------------------------------------------------------------------------
extern "C" void kernel_launch(void* const* d_in, const int* in_sizes, int n_in,
                              void* d_out, int out_size, void* d_ws, size_t ws_size,
                              hipStream_t stream) {
  (void)in_sizes; (void)n_in; (void)out_size;
  if (ws_size < 165130000) return;

  const float* fea = (const float*)d_in[0];
  const int*   gidx = (const int*)d_in[1];
  const float* xyz = (const float*)d_in[2];
  const float* W1 = (const float*)d_in[3];
  const float* g1 = (const float*)d_in[4];
  const float* b1 = (const float*)d_in[5];
  const float* m1 = (const float*)d_in[6];
  const float* v1 = (const float*)d_in[7];
  const float* W2 = (const float*)d_in[8];
  const float* g2 = (const float*)d_in[9];
  const float* b2 = (const float*)d_in[10];
  const float* m2 = (const float*)d_in[11];
  const float* v2 = (const float*)d_in[12];
  const float* W3 = (const float*)d_in[13];
  const float* g3 = (const float*)d_in[14];
  const float* b3 = (const float*)d_in[15];
  const float* m3 = (const float*)d_in[16];
  const float* v3 = (const float*)d_in[17];
  const float* Wo1 = (const float*)d_in[18];
  const float* bo1 = (const float*)d_in[19];
  const float* go = (const float*)d_in[20];
  const float* bo = (const float*)d_in[21];
  const float* mo = (const float*)d_in[22];
  const float* vo = (const float*)d_in[23];
  const float* Wo2 = (const float*)d_in[24];
  const float* bo2 = (const float*)d_in[25];

  char* ws = (char*)d_ws;
  uint16_t* pad0 = (uint16_t*)(ws);
  uint16_t* pad1 = (uint16_t*)(ws + 80289792);
  uint16_t* Wt1 = (uint16_t*)(ws + 160579584);
  uint16_t* Wt2 = (uint16_t*)(ws + 164118528);
  uint16_t* Wt3 = (uint16_t*)(ws + 165003264);
  float* s1  = (float*)(ws + 165113856 + 0 * 1024);
  float* be1 = (float*)(ws + 165113856 + 1 * 1024);
  float* s2  = (float*)(ws + 165113856 + 2 * 1024);
  float* be2 = (float*)(ws + 165113856 + 3 * 1024);
  float* s3  = (float*)(ws + 165113856 + 4 * 1024);
  float* be3 = (float*)(ws + 165113856 + 5 * 1024);
  float* so  = (float*)(ws + 165113856 + 6 * 1024);
  float* beo = (float*)(ws + 165113856 + 7 * 1024);
  uint16_t* pad2 = (uint16_t*)(ws);
  float* x3 = (float*)(ws + 20072448);

  prep_bn<<<1, 256, 0, stream>>>(g1, b1, m1, v1, g2, b2, m2, v2, g3, b3, m3, v3,
                                 go, bo, mo, vo, bo1, s1, be1, s2, be2, s3, be3, so, beo);
  wtrans<<<6912, 256, 0, stream>>>(W1, Wt1, 256, 256, 4);
  wtrans<<<1728, 256, 0, stream>>>(W2, Wt2, 64, 256, 4);
  wtrans<<<216, 256, 0, stream>>>(W3, Wt3, 32, 64, 1);
  halo_zero<<<264, 256, 0, stream>>>((uint16_t*)ws, 256);   // pad0+pad1 halos
  transpose_fea<<<1024, 256, 0, stream>>>(fea, pad0);

  // conv1: CI=256, CO=256, MH=8 (MTILE=128), waves 2x2, per-wave 64x128
  conv_mfma<256, 256, 8, 2, 2, false>
      <<<1024, 256, 0, stream>>>(pad0, Wt1, s1, be1, pad1, nullptr);

  // pad2 halo (aliases pad0 region; pad0 dead after conv1 — stream-ordered)
  halo_zero<<<132, 256, 0, stream>>>((uint16_t*)ws, 64);

  // conv2: CI=256, CO=64, MH=16 (MTILE=256), waves 4x1, per-wave 64x64
  conv_mfma<256, 64, 16, 4, 1, false>
      <<<512, 256, 0, stream>>>(pad1, Wt2, s2, be2, pad2, nullptr);

  // conv3: CI=64, CO=32, MH=16 (MTILE=256), waves 4x1, per-wave 64x32
  conv_mfma<64, 32, 16, 4, 1, true>
      <<<512, 256, 0, stream>>>(pad2, Wt3, s3, be3, nullptr, x3);

  gather_mlp<<<782, 256, 0, stream>>>(x3, gidx, xyz, Wo1, so, beo, Wo2, bo2, (float*)d_out);
}

// Round 7
// 1103.832 us; speedup vs baseline: 1.4558x; 1.2987x over previous
//
#include <hip/hip_runtime.h>
#include <stdint.h>

#define EPS 1e-5f
#define SLOPE 0.01f

typedef short bf16x8 __attribute__((ext_vector_type(8)));
typedef float f32x16 __attribute__((ext_vector_type(16)));

// round-to-nearest-even fp32 -> bf16
__device__ __forceinline__ uint16_t f2bf(float x) {
  union { float f; uint32_t u; } v; v.f = x;
  return (uint16_t)((v.u + 0x7fffu + ((v.u >> 16) & 1u)) >> 16);
}

// async global->LDS, 16B per lane; LDS dest = wave-uniform base + lane*16
__device__ __forceinline__ void g2lds16(const void* g, void* l) {
  __builtin_amdgcn_global_load_lds(
      (const __attribute__((address_space(1))) void*)g,
      (__attribute__((address_space(3))) void*)l, 16, 0, 0);
}

// ---------------------------------------------------------------------------
// prep: bn scale/bias folding.
// ---------------------------------------------------------------------------
__global__ void prep_bn(const float* g1, const float* b1, const float* m1, const float* v1,
                        const float* g2, const float* b2, const float* m2, const float* v2,
                        const float* g3, const float* b3, const float* m3, const float* v3,
                        const float* go, const float* bo, const float* mo, const float* vo,
                        const float* bo1,
                        float* s1, float* be1, float* s2, float* be2,
                        float* s3, float* be3, float* so, float* beo) {
  int t = threadIdx.x;
  if (t < 256) { float s = g1[t] / sqrtf(v1[t] + EPS); s1[t] = s; be1[t] = b1[t] - m1[t] * s; }
  if (t < 64)  { float s = g2[t] / sqrtf(v2[t] + EPS); s2[t] = s; be2[t] = b2[t] - m2[t] * s; }
  if (t < 32)  { float s = g3[t] / sqrtf(v3[t] + EPS); s3[t] = s; be3[t] = b3[t] - m3[t] * s; }
  if (t < 32)  { float s = go[t] / sqrtf(vo[t] + EPS); so[t] = s; beo[t] = bo[t] + (bo1[t] - mo[t]) * s; }
}

// ---------------------------------------------------------------------------
// weight transform: W[co][ci][27] fp32 -> Wt[t][co][ci] bf16   (r3 layout)
// ---------------------------------------------------------------------------
__global__ void wtrans(const float* __restrict__ W, uint16_t* __restrict__ Wt,
                       int CO, int CI) {
  int idx = blockIdx.x * 256 + threadIdx.x;
  int total = CO * CI * 27;
  if (idx >= total) return;
  int t = idx / (CO * CI);
  int rem = idx % (CO * CI);
  int co = rem / CI, ci = rem % CI;
  Wt[idx] = f2bf(W[((size_t)co * CI + ci) * 27 + t]);
}

// ---------------------------------------------------------------------------
// halo zero: padded buffer [NB][66][66][18][C] — zero d/h/w halo cells.
// ---------------------------------------------------------------------------
__global__ __launch_bounds__(256) void halo_zero(uint16_t* __restrict__ base, int C) {
  int dpad = blockIdx.x % 66;
  int bd = blockIdx.x / 66;
  uint16_t* slab = base + ((size_t)bd * 78408 + (size_t)dpad * 1188) * C;
  int t = threadIdx.x;
  int tc = t & 7;
  bool dHalo = (dpad == 0) | (dpad == 65);
  int n4 = C >> 6;
  for (int cell = t >> 3; cell < 1188; cell += 32) {
    int hp = cell / 18, wp = cell % 18;
    if (!(dHalo || hp == 0 || hp == 65 || wp == 0 || wp == 17)) continue;
    uint4* q = (uint4*)(slab + (size_t)cell * C + tc * (C >> 3));
    for (int i = 0; i < n4; ++i) q[i] = make_uint4(0, 0, 0, 0);
  }
}

// ---------------------------------------------------------------------------
// fea NCDHW fp32 -> pad0 NDHWC bf16, padded dims [66][66][18][256].
// ---------------------------------------------------------------------------
__global__ __launch_bounds__(256) void transpose_fea(const float* __restrict__ fea,
                                                     uint16_t* __restrict__ pad0) {
  int tid = threadIdx.x;
  int idx = blockIdx.x;
  int half = idx & 1;
  int q = (idx >> 1) & 3;
  int d = (idx >> 3) & 63;
  int b = idx >> 9;
  int s = q * 256 + tid;
  int h = s >> 4, w = s & 15;
  const float* src = fea + (size_t)(b * 256 + half * 128) * 65536 + (size_t)d * 1024 + s;
  uint16_t* dst = pad0 + ((size_t)b * 78408 +
                          (size_t)((d + 1) * 1188 + (h + 1) * 18 + (w + 1))) * 256 + half * 128;
#pragma unroll 4
  for (int c8 = 0; c8 < 16; ++c8) {
    uint16_t v[8];
#pragma unroll
    for (int j = 0; j < 8; ++j)
      v[j] = f2bf(src[(size_t)(c8 * 8 + j) * 65536]);
    *(uint4*)&dst[c8 * 8] = *(uint4*)v;
  }
}

// ---------------------------------------------------------------------------
// Implicit-GEMM 3x3x3 conv, r3 barrier structure, mfma_f32_32x32x16_bf16.
//   A: LDS, BK=64, kw-extended rows [w'0..17][mh][ci64], staged once per
//      (dh,kc), reused kw=0,1,2.  XOR swizzle u^(w'&7) (r3-proven).
//   B: [n][ci64] rows, XOR swizzle u^(row&7).  If B3: all 3 kw chunks staged
//      with A in ONE barrier pair (CO<=64 -> 3*CO*128B fits) -> 1 barrier
//      pair per (dh,kc) instead of 3.  Else (CO=256) r3 per-kw staging.
//   MFMA 32x32x16: A row=lane&31 -> (w=lane&15, mh+=bit4), k=(lane>>5)*8+j;
//   C/D col=lane&31, row=(reg&3)+8*(reg>>2)+4*(lane>>5)  [m74/m101].
// ---------------------------------------------------------------------------
template <int CI, int CO, int MH, int WM, int WN, bool B3, bool LAST>
__global__ __launch_bounds__(256, 2) void conv_mfma(const uint16_t* __restrict__ padIn,
                                                    const uint16_t* __restrict__ Wt,
                                                    const float* __restrict__ bnS,
                                                    const float* __restrict__ bnB,
                                                    uint16_t* __restrict__ padOut,
                                                    float* __restrict__ x3out) {
  constexpr int MTILE = MH * 16;
  constexpr int MPW = MTILE / WM;
  constexpr int NPW = CO / WN;
  constexpr int MT2 = MPW / 32;        // 32x32 m-tiles per wave
  constexpr int NT2 = NPW / 32;        // 32x32 n-tiles per wave
  constexpr int KC = CI / 64;
  constexpr int HB = 64 / MH;
  constexpr int AHI = MH / 8;          // A staging instrs per w'-slot
  constexpr int ROWSTR = 18 * CI;
  constexpr int BROWS = (B3 ? 3 : 1) * CO;
  constexpr int BPASS = BROWS / 32;    // 4KB staging passes

  __shared__ __align__(16) uint16_t Alds[20 * MH * 64];  // [w'][mh][ci64]
  __shared__ __align__(16) uint16_t Blds[BROWS * 64];    // [row][ci64]

  const int tid = threadIdx.x;
  const int lane = tid & 63;
  const int wv = tid >> 6;
  const int wvm = wv / WN;
  const int wvn = wv % WN;

  const int mt = blockIdx.x;
  const int b = mt / (64 * HB);
  const int r = mt % (64 * HB);
  const int d = r / HB;
  const int h0 = (r % HB) * MH;

  // B staging constants: row = tid>>3 (+32/pass), unit = tid&7, xor'd
  const int subswB = (tid & 7) ^ ((tid >> 3) & 7);
  const int rowB0 = tid >> 3;

  f32x16 acc[MT2][NT2] = {};

  const size_t bOffIn = (size_t)b * 78408 * CI;

// stage A_ext for this (dh,kc): wave wv covers w'-slots wv*5..wv*5+4
#define STAGE_A()                                                          \
  {                                                                        \
    const uint16_t* agBase = padIn + Abase + kc * 64 +                     \
                             (size_t)(lane >> 3) * ROWSTR;                 \
    _Pragma("unroll")                                                      \
    for (int p = 0; p < 5; ++p) {                                          \
      int wp = wv * 5 + p;                                                 \
      int gu = (lane & 7) ^ (wp & 7);                                      \
      _Pragma("unroll")                                                    \
      for (int hf = 0; hf < AHI; ++hf)                                     \
        g2lds16(agBase + (size_t)(hf * 8) * ROWSTR + wp * CI + gu * 8,     \
                (char*)Alds + wp * (MH * 128) + hf * 1024);                \
    }                                                                      \
  }

// one K=16 MFMA chunk for window KW, chunk KCH (0..3 within BK=64)
#define COMPUTE_CHUNK(KW, KCH)                                             \
  {                                                                        \
    bf16x8 af[MT2], bfr[NT2];                                              \
    _Pragma("unroll")                                                      \
    for (int nt = 0; nt < NT2; ++nt) {                                     \
      int row = (B3 ? (KW) * CO : 0) + wvn * NPW + nt * 32 + (lane & 31);  \
      int u = ((KCH) * 2 + (lane >> 5)) ^ (row & 7);                       \
      bfr[nt] = *(const bf16x8*)&Blds[row * 64 + u * 8];                   \
    }                                                                      \
    _Pragma("unroll")                                                      \
    for (int mtI = 0; mtI < MT2; ++mtI) {                                  \
      int wq = (lane & 15) + (KW);                                         \
      int mh = wvm * (MPW / 16) + mtI * 2 + ((lane >> 4) & 1);             \
      int u = ((KCH) * 2 + (lane >> 5)) ^ (wq & 7);                        \
      af[mtI] = *(const bf16x8*)&Alds[wq * (MH * 64) + mh * 64 + u * 8];   \
    }                                                                      \
    _Pragma("unroll")                                                      \
    for (int mtI = 0; mtI < MT2; ++mtI)                                    \
      _Pragma("unroll")                                                    \
      for (int nt = 0; nt < NT2; ++nt)                                     \
        acc[mtI][nt] = __builtin_amdgcn_mfma_f32_32x32x16_bf16(            \
            af[mtI], bfr[nt], acc[mtI][nt], 0, 0, 0);                      \
  }

  for (int dh = 0; dh < 9; ++dh) {
    const int kd = dh / 3, kh = dh % 3;
    const size_t Abase = bOffIn + (size_t)((d + kd) * 1188 + (h0 + kh) * 18) * CI;
    for (int kc = 0; kc < KC; ++kc) {
      if (B3) {
        // one barrier pair: A + B(all 3 kw)
        __syncthreads();
        STAGE_A();
        {
#pragma unroll
          for (int p = 0; p < BPASS; ++p) {
            int row = rowB0 + 32 * p;
            int kwi = row / CO;
            int cor = row - kwi * CO;
            const uint16_t* bg = Wt + ((size_t)(dh * 3 + kwi) * CO + cor) * CI +
                                 kc * 64 + subswB * 8;
            g2lds16(bg, (char*)Blds + p * 4096 + wv * 1024);
          }
        }
        __syncthreads();
#pragma unroll
        for (int kw = 0; kw < 3; ++kw) {
          COMPUTE_CHUNK(kw, 0); COMPUTE_CHUNK(kw, 1);
          COMPUTE_CHUNK(kw, 2); COMPUTE_CHUNK(kw, 3);
        }
      } else {
        // r3 structure: per-kw barrier pair, A staged at kw==0
#pragma unroll 1
        for (int kw = 0; kw < 3; ++kw) {
          __syncthreads();
          if (kw == 0) STAGE_A();
          {
            const uint16_t* bg = Wt + (size_t)((dh * 3 + kw) * CO) * CI +
                                 kc * 64 + subswB * 8;
#pragma unroll
            for (int p = 0; p < BPASS; ++p)
              g2lds16(bg + (size_t)(rowB0 + 32 * p) * CI,
                      (char*)Blds + p * 4096 + wv * 1024);
          }
          __syncthreads();
          COMPUTE_CHUNK(kw, 0); COMPUTE_CHUNK(kw, 1);
          COMPUTE_CHUNK(kw, 2); COMPUTE_CHUNK(kw, 3);
        }
      }
    }
  }
#undef STAGE_A
#undef COMPUTE_CHUNK

  // epilogue: y = x*s + beta, LeakyReLU
  // C/D 32x32: col=lane&31, row=(reg&3)+8*(reg>>2)+4*(lane>>5)
  const int col = lane & 31;
  const int rbase = 4 * (lane >> 5);
#pragma unroll
  for (int nt = 0; nt < NT2; ++nt) {
    const int co = wvn * NPW + nt * 32 + col;
    const float sv = bnS[co];
    const float bv = bnB[co];
#pragma unroll
    for (int mtI = 0; mtI < MT2; ++mtI) {
#pragma unroll
      for (int reg = 0; reg < 16; ++reg) {
        int m = wvm * MPW + mtI * 32 + (reg & 3) + 8 * (reg >> 2) + rbase;
        float v = acc[mtI][nt][reg] * sv + bv;
        v = v > 0.f ? v : SLOPE * v;
        int mh = m >> 4, w = m & 15;
        if (!LAST) {
          size_t o = ((size_t)b * 78408 +
                      (size_t)((d + 1) * 1188 + (h0 + mh + 1) * 18 + (w + 1))) * CO + co;
          padOut[o] = f2bf(v);
        } else {
          size_t o = ((size_t)b * 65536 + (size_t)((d * 64 + h0 + mh) * 16 + w)) * 32 + co;
          x3out[o] = v;
        }
      }
    }
  }
}

// ---------------------------------------------------------------------------
// gather + point MLP, all fp32. One thread per point.
// ---------------------------------------------------------------------------
__global__ __launch_bounds__(256) void gather_mlp(const float* __restrict__ x3,
                                                  const int* __restrict__ gidx,
                                                  const float* __restrict__ xyz,
                                                  const float* __restrict__ Wo1,
                                                  const float* __restrict__ so,
                                                  const float* __restrict__ beo,
                                                  const float* __restrict__ Wo2,
                                                  const float* __restrict__ bo2,
                                                  float* __restrict__ out) {
  __shared__ __align__(16) float w1[35 * 32];
  __shared__ float w2[32 * 3];
  __shared__ float sS[32], sB[32], b2s[3];
  int tid = threadIdx.x;
  for (int i = tid; i < 1120; i += 256) w1[i] = Wo1[i];
  if (tid < 96) w2[tid] = Wo2[tid];
  if (tid < 32) { sS[tid] = so[tid]; sB[tid] = beo[tid]; }
  if (tid < 3) b2s[tid] = bo2[tid];
  __syncthreads();

  int idx = blockIdx.x * 256 + tid;
  if (idx >= 200000) return;
  int b = idx >= 100000 ? 1 : 0;
  int gb = idx * 3;
  int i0 = gidx[gb], i1 = gidx[gb + 1], i2 = gidx[gb + 2];
  const float* pt = x3 + ((size_t)b * 65536 + (size_t)((i0 * 64 + i1) * 16 + i2)) * 32;

  float h[35];
#pragma unroll
  for (int q = 0; q < 8; ++q) {
    float4 v = *(const float4*)(pt + q * 4);
    h[q * 4] = v.x; h[q * 4 + 1] = v.y; h[q * 4 + 2] = v.z; h[q * 4 + 3] = v.w;
  }
  h[32] = xyz[gb]; h[33] = xyz[gb + 1]; h[34] = xyz[gb + 2];

  float a[32];
#pragma unroll
  for (int j = 0; j < 32; ++j) a[j] = 0.f;
#pragma unroll
  for (int k = 0; k < 35; ++k) {
    float hk = h[k];
    const float4* wr = (const float4*)(w1 + k * 32);
#pragma unroll
    for (int q = 0; q < 8; ++q) {
      float4 wv = wr[q];
      a[q * 4 + 0] += hk * wv.x;
      a[q * 4 + 1] += hk * wv.y;
      a[q * 4 + 2] += hk * wv.z;
      a[q * 4 + 3] += hk * wv.w;
    }
  }
  float o0 = b2s[0], o1 = b2s[1], o2 = b2s[2];
#pragma unroll
  for (int j = 0; j < 32; ++j) {
    float y = a[j] * sS[j] + sB[j];
    y = y > 0.f ? y : 0.f;
    o0 += y * w2[j * 3 + 0];
    o1 += y * w2[j * 3 + 1];
    o2 += y * w2[j * 3 + 2];
  }
  out[gb] = o0; out[gb + 1] = o1; out[gb + 2] = o2;
}

// ---------------------------------------------------------------------------
// workspace layout: unchanged from r3.
// ---------------------------------------------------------------------------
extern "C" void kernel_launch(void* const* d_in, const int* in_sizes, int n_in,
                              void* d_out, int out_size, void* d_ws, size_t ws_size,
                              hipStream_t stream) {
  (void)in_sizes; (void)n_in; (void)out_size;
  if (ws_size < 165130000) return;

  const float* fea = (const float*)d_in[0];
  const int*   gidx = (const int*)d_in[1];
  const float* xyz = (const float*)d_in[2];
  const float* W1 = (const float*)d_in[3];
  const float* g1 = (const float*)d_in[4];
  const float* b1 = (const float*)d_in[5];
  const float* m1 = (const float*)d_in[6];
  const float* v1 = (const float*)d_in[7];
  const float* W2 = (const float*)d_in[8];
  const float* g2 = (const float*)d_in[9];
  const float* b2 = (const float*)d_in[10];
  const float* m2 = (const float*)d_in[11];
  const float* v2 = (const float*)d_in[12];
  const float* W3 = (const float*)d_in[13];
  const float* g3 = (const float*)d_in[14];
  const float* b3 = (const float*)d_in[15];
  const float* m3 = (const float*)d_in[16];
  const float* v3 = (const float*)d_in[17];
  const float* Wo1 = (const float*)d_in[18];
  const float* bo1 = (const float*)d_in[19];
  const float* go = (const float*)d_in[20];
  const float* bo = (const float*)d_in[21];
  const float* mo = (const float*)d_in[22];
  const float* vo = (const float*)d_in[23];
  const float* Wo2 = (const float*)d_in[24];
  const float* bo2 = (const float*)d_in[25];

  char* ws = (char*)d_ws;
  uint16_t* pad0 = (uint16_t*)(ws);
  uint16_t* pad1 = (uint16_t*)(ws + 80289792);
  uint16_t* Wt1 = (uint16_t*)(ws + 160579584);
  uint16_t* Wt2 = (uint16_t*)(ws + 164118528);
  uint16_t* Wt3 = (uint16_t*)(ws + 165003264);
  float* s1  = (float*)(ws + 165113856 + 0 * 1024);
  float* be1 = (float*)(ws + 165113856 + 1 * 1024);
  float* s2  = (float*)(ws + 165113856 + 2 * 1024);
  float* be2 = (float*)(ws + 165113856 + 3 * 1024);
  float* s3  = (float*)(ws + 165113856 + 4 * 1024);
  float* be3 = (float*)(ws + 165113856 + 5 * 1024);
  float* so  = (float*)(ws + 165113856 + 6 * 1024);
  float* beo = (float*)(ws + 165113856 + 7 * 1024);
  uint16_t* pad2 = (uint16_t*)(ws);
  float* x3 = (float*)(ws + 20072448);

  prep_bn<<<1, 256, 0, stream>>>(g1, b1, m1, v1, g2, b2, m2, v2, g3, b3, m3, v3,
                                 go, bo, mo, vo, bo1, s1, be1, s2, be2, s3, be3, so, beo);
  wtrans<<<6912, 256, 0, stream>>>(W1, Wt1, 256, 256);
  wtrans<<<1728, 256, 0, stream>>>(W2, Wt2, 64, 256);
  wtrans<<<216, 256, 0, stream>>>(W3, Wt3, 32, 64);
  halo_zero<<<264, 256, 0, stream>>>((uint16_t*)ws, 256);   // pad0+pad1 halos
  transpose_fea<<<1024, 256, 0, stream>>>(fea, pad0);

  // conv1: CI=256, CO=256, MH=8 (MTILE=128), waves 2x2, per-wave 64x128
  conv_mfma<256, 256, 8, 2, 2, false, false>
      <<<1024, 256, 0, stream>>>(pad0, Wt1, s1, be1, pad1, nullptr);

  // pad2 halo (aliases pad0 region; pad0 dead after conv1 — stream-ordered)
  halo_zero<<<132, 256, 0, stream>>>((uint16_t*)ws, 64);

  // conv2: CI=256, CO=64, MH=16 (MTILE=256), waves 4x1, per-wave 64x64, B3
  conv_mfma<256, 64, 16, 4, 1, true, false>
      <<<512, 256, 0, stream>>>(pad1, Wt2, s2, be2, pad2, nullptr);

  // conv3: CI=64, CO=32, MH=16 (MTILE=256), waves 4x1, per-wave 64x32, B3
  conv_mfma<64, 32, 16, 4, 1, true, true>
      <<<512, 256, 0, stream>>>(pad2, Wt3, s3, be3, nullptr, x3);

  gather_mlp<<<782, 256, 0, stream>>>(x3, gidx, xyz, Wo1, so, beo, Wo2, bo2, (float*)d_out);
}